// Round 1
// baseline (183.691 us; speedup 1.0000x reference)
//
#include <hip/hip_runtime.h>
#include <cstddef>

// JastrowNet: B=512, n_elec=32 (16 up/16 down), n_atoms=8, dist_feat=32,
// kernel=8, embed=16, layers=2, w-hidden=16.
// One block per batch element; both layers fused (no grid sync needed since
// the heavy edge-MLP is x-independent and the x-dependent einsum is intra-block).

#define NB   512
#define NE   32
#define NA   8
#define NF   32
#define NH   16
#define NK   8
#define NEMB 16
#define NL   2
#define WE_STRIDE (NE*NK + 8)   // 264 floats: i-stride ≡ 8 mod 32 banks -> 2-way max (free)
#define WN_STRIDE ((NA+1)*NK)   // 72

__device__ __forceinline__ float ssp(float v){
    // shifted softplus: log(1+exp(v)) - log(2), overflow-safe
    return fmaxf(v, 0.f) + __logf(1.f + __expf(-fabsf(v))) - 0.6931471805599453f;
}

// One edge row through the 32->16->8 ssp MLP. Weights come from LDS
// (wave-broadcast reads, vectorized as float4).
__device__ __forceinline__ void compute_w(const float4 ev[8],
        const float* __restrict__ sW1, const float* __restrict__ sB1,
        const float* __restrict__ sW2, const float* __restrict__ sB2,
        float w[NK])
{
    float e32[NF];
#pragma unroll
    for (int q = 0; q < 8; q++){
        e32[4*q+0] = ev[q].x; e32[4*q+1] = ev[q].y;
        e32[4*q+2] = ev[q].z; e32[4*q+3] = ev[q].w;
    }
    float h1[NH];
#pragma unroll
    for (int h = 0; h < NH; h++) h1[h] = sB1[h];
#pragma unroll
    for (int f = 0; f < NF; f++){
        float ef = e32[f];
        const float4* w4 = (const float4*)(sW1 + f*NH);
#pragma unroll
        for (int q = 0; q < 4; q++){
            float4 wv = w4[q];
            h1[4*q+0] = fmaf(ef, wv.x, h1[4*q+0]);
            h1[4*q+1] = fmaf(ef, wv.y, h1[4*q+1]);
            h1[4*q+2] = fmaf(ef, wv.z, h1[4*q+2]);
            h1[4*q+3] = fmaf(ef, wv.w, h1[4*q+3]);
        }
    }
#pragma unroll
    for (int h = 0; h < NH; h++) h1[h] = ssp(h1[h]);
    float acc[NK];
#pragma unroll
    for (int k = 0; k < NK; k++) acc[k] = sB2[k];
#pragma unroll
    for (int h = 0; h < NH; h++){
        float hv = h1[h];
        const float4* w4 = (const float4*)(sW2 + h*NK);
#pragma unroll
        for (int q = 0; q < 2; q++){
            float4 wv = w4[q];
            acc[4*q+0] = fmaf(hv, wv.x, acc[4*q+0]);
            acc[4*q+1] = fmaf(hv, wv.y, acc[4*q+1]);
            acc[4*q+2] = fmaf(hv, wv.z, acc[4*q+2]);
            acc[4*q+3] = fmaf(hv, wv.w, acc[4*q+3]);
        }
    }
#pragma unroll
    for (int k = 0; k < NK; k++) w[k] = ssp(acc[k]);
}

extern "C" __global__ void __launch_bounds__(256, 2)
jastrow_kernel(const float* __restrict__ edges_elec,
               const float* __restrict__ edges_nuc,
               const float* __restrict__ X_emb,
               const float* __restrict__ Yk,
               const float* __restrict__ wW1, const float* __restrict__ wb1,
               const float* __restrict__ wW2, const float* __restrict__ wb2,
               const float* __restrict__ hW,  const float* __restrict__ hb,
               const float* __restrict__ gW,  const float* __restrict__ gb,
               const float* __restrict__ orbW,
               float* __restrict__ out)
{
    __shared__ __align__(16) float s_wW1[NL*3*NF*NH];   // 12 KB
    __shared__ float s_wb1[NL*3*NH];
    __shared__ __align__(16) float s_wW2[NL*3*NH*NK];   // 3 KB
    __shared__ float s_wb2[NL*3*NK];
    __shared__ float s_hW[NL*NEMB*NK];
    __shared__ float s_hb[NL*NK];
    __shared__ float s_gW[NL*NK*NEMB];
    __shared__ float s_gb[NL*NEMB];
    __shared__ float s_Y[NA*NK];
    __shared__ float s_orb[NEMB];
    __shared__ float s_x[NE*NEMB];                      // 2 KB
    __shared__ float s_hx[NE*NK];
    __shared__ float s_z[NE*NK];
    __shared__ float s_we[NE*WE_STRIDE];                // ~33 KB
    __shared__ float s_wn[NE*WN_STRIDE];                // ~9 KB
    __shared__ float s_red[4];

    const int b   = blockIdx.x;
    const int tid = threadIdx.x;

    // ---- stage all weights into LDS (broadcast-read later) ----
    for (int i2 = tid; i2 < NL*3*NF*NH; i2 += 256) s_wW1[i2] = wW1[i2];
    for (int i2 = tid; i2 < NL*3*NH;    i2 += 256) s_wb1[i2] = wb1[i2];
    for (int i2 = tid; i2 < NL*3*NH*NK; i2 += 256) s_wW2[i2] = wW2[i2];
    for (int i2 = tid; i2 < NL*3*NK;    i2 += 256) s_wb2[i2] = wb2[i2];
    for (int i2 = tid; i2 < NL*NEMB*NK; i2 += 256) s_hW[i2]  = hW[i2];
    for (int i2 = tid; i2 < NL*NK;      i2 += 256) s_hb[i2]  = hb[i2];
    for (int i2 = tid; i2 < NL*NK*NEMB; i2 += 256) s_gW[i2]  = gW[i2];
    for (int i2 = tid; i2 < NL*NEMB;    i2 += 256) s_gb[i2]  = gb[i2];
    for (int i2 = tid; i2 < NA*NK;      i2 += 256) s_Y[i2]   = Yk[i2];
    for (int i2 = tid; i2 < NEMB;       i2 += 256) s_orb[i2] = orbW[i2];
    // initial embeddings by spin (i<16 -> up=0, else down=1)
    for (int i2 = tid; i2 < NE*NEMB; i2 += 256){
        int row = i2 >> 4; int spin = row >> 4;
        s_x[i2] = X_emb[spin*NEMB + (i2 & 15)];
    }
    __syncthreads();

    const float* base_e = edges_elec + (size_t)b * NE * NE * NF;
    const float* base_n = edges_nuc  + (size_t)b * NE * NA * NF;

    for (int l = 0; l < NL; l++){
        // ---- electron-electron filters: 1024 rows, 4 per thread, prefetched ----
        float4 ev[8];
        {
            const float4* p = (const float4*)(base_e + (size_t)tid * NF);
#pragma unroll
            for (int q = 0; q < 8; q++) ev[q] = p[q];
        }
#pragma unroll 1
        for (int it = 0; it < 4; it++){
            int row = it*256 + tid;
            int i = row >> 5, j = row & 31;
            int c = ((i >> 4) ^ (j >> 4)) & 1;   // 0 = same spin, 1 = anti
            // prefetch next row (last slot prefetches this thread's nuclear row)
            const float* nxt = (it < 3)
                ? (base_e + (size_t)(row + 256) * NF)
                : (base_n + (size_t)((tid >> 3) * NA + (tid & 7)) * NF);
            float4 evn[8];
            {
                const float4* p = (const float4*)nxt;
#pragma unroll
                for (int q = 0; q < 8; q++) evn[q] = p[q];
            }
            float w[NK];
            compute_w(ev, &s_wW1[(l*3+c)*NF*NH], &s_wb1[(l*3+c)*NH],
                      &s_wW2[(l*3+c)*NH*NK], &s_wb2[(l*3+c)*NK], w);
            float mask = (i == j) ? 0.f : 1.f;   // diagonal excluded from 'same'
            float* dst = &s_we[i*WE_STRIDE + j*NK];
#pragma unroll
            for (int k = 0; k < NK; k++) dst[k] = w[k] * mask;
#pragma unroll
            for (int q = 0; q < 8; q++) ev[q] = evn[q];
        }
        // ---- electron-nuclear filters: 256 rows, 1 per thread (already in ev) ----
        {
            int i = tid >> 3, m = tid & 7;
            float w[NK];
            compute_w(ev, &s_wW1[(l*3+2)*NF*NH], &s_wb1[(l*3+2)*NH],
                      &s_wW2[(l*3+2)*NH*NK], &s_wb2[(l*3+2)*NK], w);
            float* dst = &s_wn[i*WN_STRIDE + m*NK];
#pragma unroll
            for (int k = 0; k < NK; k++) dst[k] = w[k];
        }
        // ---- hx = ssp(x @ hW + hb), one (i,k) per thread ----
        {
            int i = tid >> 3, k = tid & 7;
            float acc = s_hb[l*NK + k];
#pragma unroll
            for (int e = 0; e < NEMB; e++)
                acc = fmaf(s_x[i*NEMB + e], s_hW[(l*NEMB + e)*NK + k], acc);
            s_hx[tid] = ssp(acc);
        }
        __syncthreads();
        // ---- z[i,k] = sum_j we[i,j,k]*hx[j,k] + sum_m wn[i,m,k]*Y[m,k] ----
        {
            int i = tid >> 3, k = tid & 7;
            float acc = 0.f;
#pragma unroll
            for (int j = 0; j < NE; j++)
                acc = fmaf(s_we[i*WE_STRIDE + j*NK + k], s_hx[j*NK + k], acc);
#pragma unroll
            for (int m = 0; m < NA; m++)
                acc = fmaf(s_wn[i*WN_STRIDE + m*NK + k], s_Y[m*NK + k], acc);
            s_z[tid] = acc;
        }
        __syncthreads();
        // ---- x += z @ gW + gb, two (i,e) entries per thread ----
#pragma unroll
        for (int q = 0; q < 2; q++){
            int idx = q*256 + tid;
            int i = idx >> 4, e = idx & 15;
            float acc = s_gb[l*NEMB + e];
#pragma unroll
            for (int k = 0; k < NK; k++)
                acc = fmaf(s_z[i*NK + k], s_gW[(l*NK + k)*NEMB + e], acc);
            s_x[idx] += acc;
        }
        __syncthreads();
    }

    // ---- readout: out[b] = sum_{i,e} x[i,e]*orbW[e] ----
    float part = (s_x[tid] + s_x[tid + 256]) * s_orb[tid & 15];
#pragma unroll
    for (int off = 32; off > 0; off >>= 1) part += __shfl_down(part, off, 64);
    if ((tid & 63) == 0) s_red[tid >> 6] = part;
    __syncthreads();
    if (tid == 0) out[b] = s_red[0] + s_red[1] + s_red[2] + s_red[3];
}

extern "C" void kernel_launch(void* const* d_in, const int* in_sizes, int n_in,
                              void* d_out, int out_size, void* d_ws, size_t ws_size,
                              hipStream_t stream)
{
    jastrow_kernel<<<NB, 256, 0, stream>>>(
        (const float*)d_in[0],  (const float*)d_in[1],  (const float*)d_in[2],
        (const float*)d_in[3],  (const float*)d_in[4],  (const float*)d_in[5],
        (const float*)d_in[6],  (const float*)d_in[7],  (const float*)d_in[8],
        (const float*)d_in[9],  (const float*)d_in[10], (const float*)d_in[11],
        (const float*)d_in[12], (float*)d_out);
}